// Round 1
// baseline (185.592 us; speedup 1.0000x reference)
//
#include <hip/hip_runtime.h>

#define DEV static __device__ __forceinline__

typedef __bf16 bf16x8 __attribute__((ext_vector_type(8)));
typedef float f32x4 __attribute__((ext_vector_type(4)));
typedef unsigned int uint4v __attribute__((ext_vector_type(4)));
typedef unsigned short ushort4v __attribute__((ext_vector_type(4)));
using u16 = unsigned short;

#define NN 2048
#define DIMD 1024

DEV u16 f2bf(float f) {
    unsigned u = __builtin_bit_cast(unsigned, f);
    u += 0x7FFFu + ((u >> 16) & 1u);
    return (u16)(u >> 16);
}
DEV float bf2f(u16 s) {
    unsigned u = ((unsigned)s) << 16;
    return __builtin_bit_cast(float, u);
}
DEV bf16x8 load16(const u16* p) { return __builtin_bit_cast(bf16x8, *(const uint4v*)p); }
DEV f32x4 mfma16(bf16x8 a, bf16x8 b, f32x4 c) {
    return __builtin_amdgcn_mfma_f32_16x16x32_bf16(a, b, c, 0, 0, 0);
}
DEV float wredsum(float v) {
#pragma unroll
    for (int o = 32; o; o >>= 1) v += __shfl_xor(v, o);
    return v;
}

// ---------------- prep kernels ----------------

__global__ __launch_bounds__(256) void k_pack_x(const float* __restrict__ x,
                                                u16* __restrict__ xb, int n4) {
    int i = blockIdx.x * 256 + threadIdx.x;
    if (i >= n4) return;
    float4 v = ((const float4*)x)[i];
    ushort4v o;
    o[0] = f2bf(v.x); o[1] = f2bf(v.y); o[2] = f2bf(v.z); o[3] = f2bf(v.w);
    *(ushort4v*)(xb + (size_t)i * 4) = o;
}

// dst[n][k] = src[k][n], 1024x1024, fp32 -> bf16
__global__ __launch_bounds__(256) void k_transpose_w(const float* __restrict__ s0,
                                                     const float* __restrict__ s1,
                                                     const float* __restrict__ s2,
                                                     const float* __restrict__ s3,
                                                     u16* __restrict__ wqkv_t,
                                                     u16* __restrict__ wo_t) {
    __shared__ float tile[32][33];
    int z = blockIdx.z;
    const float* src = (z == 0) ? s0 : (z == 1) ? s1 : (z == 2) ? s2 : s3;
    u16* dst = (z < 3) ? (wqkv_t + (size_t)z * 1024 * 1024) : wo_t;
    int tx = threadIdx.x & 31, ty = threadIdx.x >> 5;  // ty 0..7
    int kb = blockIdx.y * 32, nb = blockIdx.x * 32;
#pragma unroll
    for (int j = 0; j < 4; ++j)
        tile[ty + 8 * j][tx] = src[(size_t)(kb + ty + 8 * j) * 1024 + nb + tx];
    __syncthreads();
#pragma unroll
    for (int j = 0; j < 4; ++j)
        dst[(size_t)(nb + ty + 8 * j) * 1024 + kb + tx] = f2bf(tile[tx][ty + 8 * j]);
}

__global__ __launch_bounds__(256) void k_pack_bias(const float* __restrict__ bq,
                                                   const float* __restrict__ bk,
                                                   const float* __restrict__ bv,
                                                   float* __restrict__ bqkv) {
    int i = blockIdx.x * 256 + threadIdx.x;
    if (i >= 3072) return;
    bqkv[i] = (i < 1024) ? bq[i] : (i < 2048) ? bk[i - 1024] : bv[i - 2048];
}

// ---------------- GEMM: C[m][n] = A[m][K] * Bt[n][K]^T, K=1024 ----------------
// MODE 0: out bf16 = acc + bias[n]          (ldc = Ncols)
// MODE 1: out fp32 = (acc + bias[n])*gamma[n]
template <int MODE>
__global__ __launch_bounds__(256) void k_gemm(const u16* __restrict__ A,
                                              const u16* __restrict__ Bt,
                                              const float* __restrict__ bias,
                                              const float* __restrict__ gamma,
                                              void* __restrict__ out, int ldc) {
    __shared__ u16 As[128 * 40];  // 80B rows: breaks 64B-row bank aliasing
    __shared__ u16 Bs[128 * 40];
    const int K = 1024;
    const int m0 = blockIdx.x * 128, n0 = blockIdx.y * 128;
    const int tid = threadIdx.x;
    const int lane = tid & 63, w = tid >> 6;
    const int wr = w >> 1, wc = w & 1;
    const int li = lane & 15, g = lane >> 4;
    const int r1 = tid >> 2, ch = tid & 3;

    f32x4 acc[4][4] = {};

    const u16* Ap = A + (size_t)(m0 + r1) * K + ch * 8;
    const u16* Ap2 = Ap + (size_t)64 * K;
    const u16* Bp = Bt + (size_t)(n0 + r1) * K + ch * 8;
    const u16* Bp2 = Bp + (size_t)64 * K;
    u16* As1 = &As[r1 * 40 + ch * 8];
    u16* As2 = &As[(64 + r1) * 40 + ch * 8];
    u16* Bs1 = &Bs[r1 * 40 + ch * 8];
    u16* Bs2 = &Bs[(64 + r1) * 40 + ch * 8];

    for (int k0 = 0; k0 < K; k0 += 32) {
        uint4v a1 = *(const uint4v*)(Ap + k0);
        uint4v a2 = *(const uint4v*)(Ap2 + k0);
        uint4v b1 = *(const uint4v*)(Bp + k0);
        uint4v b2 = *(const uint4v*)(Bp2 + k0);
        __syncthreads();
        *(uint4v*)As1 = a1; *(uint4v*)As2 = a2;
        *(uint4v*)Bs1 = b1; *(uint4v*)Bs2 = b2;
        __syncthreads();
        bf16x8 af[4], bfv[4];
#pragma unroll
        for (int mi = 0; mi < 4; ++mi)
            af[mi] = load16(&As[(wr * 64 + mi * 16 + li) * 40 + g * 8]);
#pragma unroll
        for (int ni = 0; ni < 4; ++ni)
            bfv[ni] = load16(&Bs[(wc * 64 + ni * 16 + li) * 40 + g * 8]);
#pragma unroll
        for (int mi = 0; mi < 4; ++mi)
#pragma unroll
            for (int ni = 0; ni < 4; ++ni)
                acc[mi][ni] = mfma16(af[mi], bfv[ni], acc[mi][ni]);
    }

#pragma unroll
    for (int mi = 0; mi < 4; ++mi) {
        int row = m0 + wr * 64 + mi * 16 + 4 * g;  // C/D: row = 4*(lane>>4)+r
#pragma unroll
        for (int ni = 0; ni < 4; ++ni) {
            int col = n0 + wc * 64 + ni * 16 + li;  // C/D: col = lane&15
            float bv_ = bias[col];
            f32x4 v = acc[mi][ni];
            if (MODE == 0) {
                u16* o = (u16*)out;
#pragma unroll
                for (int r = 0; r < 4; ++r)
                    o[(size_t)(row + r) * ldc + col] = f2bf(v[r] + bv_);
            } else {
                float gv = gamma[col];
                float* o = (float*)out;
#pragma unroll
                for (int r = 0; r < 4; ++r)
                    o[(size_t)(row + r) * ldc + col] = (v[r] + bv_) * gv;
            }
        }
    }
}

// ---------------- LayerNorm(q,k over D=64) + repack, V transpose ----------------
// qkv: [4096][3072] bf16 (q|k|v). Out: Qn,Kn [bh][n][64] bf16; Vt [bh][64][N] bf16.
__global__ __launch_bounds__(256) void k_ln_repack(const u16* __restrict__ qkv,
                                                   const float* __restrict__ qs,
                                                   const float* __restrict__ qb,
                                                   const float* __restrict__ ks,
                                                   const float* __restrict__ kb,
                                                   u16* __restrict__ Qn,
                                                   u16* __restrict__ Kn,
                                                   u16* __restrict__ Vt) {
    __shared__ u16 vtile[64][72];
    const int bh = blockIdx.y, b = bh >> 4, h = bh & 15;
    const int n0 = blockIdx.x * 64;
    const int tid = threadIdx.x;
    const int wv = tid >> 6, lane = tid & 63;  // lane == d
    const float qsv = qs[lane], qbv = qb[lane], ksv = ks[lane], kbv = kb[lane];
    for (int rr = 0; rr < 16; ++rr) {
        const int nl = wv * 16 + rr;
        const int n = n0 + nl;
        const size_t base = (size_t)(b * NN + n) * 3072 + h * 64 + lane;
        float qf = bf2f(qkv[base]);
        float kf = bf2f(qkv[base + 1024]);
        float vf = bf2f(qkv[base + 2048]);
        float mq = wredsum(qf) * (1.0f / 64.0f);
        float dq = qf - mq;
        float vq = wredsum(dq * dq) * (1.0f / 64.0f);
        Qn[((size_t)bh * NN + n) * 64 + lane] = f2bf(dq * rsqrtf(vq + 1e-6f) * qsv + qbv);
        float mk = wredsum(kf) * (1.0f / 64.0f);
        float dk = kf - mk;
        float vk = wredsum(dk * dk) * (1.0f / 64.0f);
        Kn[((size_t)bh * NN + n) * 64 + lane] = f2bf(dk * rsqrtf(vk + 1e-6f) * ksv + kbv);
        vtile[nl][lane] = f2bf(vf);
    }
    __syncthreads();
    const int d = tid >> 2, c = tid & 3;
    alignas(16) u16 tmp[16];
#pragma unroll
    for (int k2 = 0; k2 < 16; ++k2) tmp[k2] = vtile[16 * c + k2][d];
    const size_t vbase = ((size_t)bh * 64 + d) * NN + n0 + 16 * c;
    *(uint4v*)(Vt + vbase) = *(const uint4v*)&tmp[0];
    *(uint4v*)(Vt + vbase + 8) = *(const uint4v*)&tmp[8];
}

// ---------------- fused sigmoid attention ----------------
// Per block: one (b,h), 64 query rows. S^T = K·Q^T, sigmoid, O^T += V^T·P^T.
// P routed through LDS in fragment-linear layout (conflict-free b128 reads).
__global__ __launch_bounds__(256) void k_attn(const u16* __restrict__ Qn,
                                              const u16* __restrict__ Kn,
                                              const u16* __restrict__ Vt,
                                              const float* __restrict__ ib,
                                              u16* __restrict__ attn_out) {
    __shared__ u16 P[8 * 64 * 8];  // [frag = t*2+c][lane][8 bf16] = 8KB
    const int bh = blockIdx.y, b = bh >> 4, h = bh & 15;
    const int i0 = blockIdx.x * 64;
    const int tid = threadIdx.x;
    const int w = tid >> 6, lane = tid & 63;
    const int li = lane & 15, g = lane >> 4;
    const float sbias = ib[0];
    const u16* Qb = Qn + (size_t)bh * NN * 64;
    const u16* Kb = Kn + (size_t)bh * NN * 64;
    const u16* Vb = Vt + (size_t)bh * 64 * NN;

    // Q fragments (B-operand of S^T): Q[i0+16t+li][32c+8g .. +8], reused all iters
    bf16x8 qf[4][2];
#pragma unroll
    for (int t = 0; t < 4; ++t)
#pragma unroll
        for (int c = 0; c < 2; ++c)
            qf[t][c] = load16(Qb + (size_t)(i0 + 16 * t + li) * 64 + 32 * c + 8 * g);

    f32x4 accO[4] = {};
    // P writer slot: frag c=w>>1, lane' = li + 16*(2*(w&1)+(g>>1)), half = g&1
    const int wrl = li + 16 * (2 * (w & 1) + (g >> 1));
    const int wro = 4 * (g & 1);

    for (int j0 = 0; j0 < NN; j0 += 64) {
        // phase 1: S^T[j][i] for j in [j0+16w, +16), all 64 i
        bf16x8 kf[2];
#pragma unroll
        for (int c = 0; c < 2; ++c)
            kf[c] = load16(Kb + (size_t)(j0 + 16 * w + li) * 64 + 32 * c + 8 * g);
        f32x4 sa[4] = {};
#pragma unroll
        for (int t = 0; t < 4; ++t) {
            sa[t] = mfma16(kf[0], qf[t][0], sa[t]);
            sa[t] = mfma16(kf[1], qf[t][1], sa[t]);
        }
        __syncthreads();  // previous iteration's P reads complete
#pragma unroll
        for (int t = 0; t < 4; ++t) {
            ushort4v p4;
#pragma unroll
            for (int r = 0; r < 4; ++r) {
                float z = sa[t][r] + sbias;
                p4[r] = f2bf(__builtin_amdgcn_rcpf(1.0f + __expf(-z)));
            }
            *(ushort4v*)&P[((t * 2 + (w >> 1)) * 64 + wrl) * 8 + wro] = p4;
        }
        __syncthreads();
        // phase 2: O^T[d][i] += V^T[d][j] P^T[j][i], d in [16w, +16)
        bf16x8 vf[2];
#pragma unroll
        for (int c = 0; c < 2; ++c)
            vf[c] = load16(Vb + (size_t)(16 * w + li) * NN + j0 + 32 * c + 8 * g);
#pragma unroll
        for (int t = 0; t < 4; ++t) {
#pragma unroll
            for (int c = 0; c < 2; ++c) {
                bf16x8 pf = load16(&P[((t * 2 + c) * 64 + lane) * 8]);
                accO[t] = mfma16(vf[c], pf, accO[t]);
            }
        }
    }

    // epilogue: O^T C/D tile -> attn_out[(b*N+i)][h*64+d] bf16
#pragma unroll
    for (int t = 0; t < 4; ++t) {
        int i = i0 + 16 * t + li;
        int d0 = 16 * w + 4 * g;
        ushort4v o4;
#pragma unroll
        for (int r = 0; r < 4; ++r) o4[r] = f2bf(accO[t][r]);
        *(ushort4v*)&attn_out[(size_t)(b * NN + i) * 1024 + h * 64 + d0] = o4;
    }
}

// ---------------- launch ----------------

extern "C" void kernel_launch(void* const* d_in, const int* in_sizes, int n_in,
                              void* d_out, int out_size, void* d_ws, size_t ws_size,
                              hipStream_t stream) {
    (void)in_sizes; (void)n_in; (void)out_size; (void)ws_size;
    const float* x     = (const float*)d_in[0];
    const float* Wq    = (const float*)d_in[1];
    const float* bq    = (const float*)d_in[2];
    const float* Wk    = (const float*)d_in[3];
    const float* bk    = (const float*)d_in[4];
    const float* Wv    = (const float*)d_in[5];
    const float* bv    = (const float*)d_in[6];
    const float* qn_s  = (const float*)d_in[7];
    const float* qn_b  = (const float*)d_in[8];
    const float* kn_s  = (const float*)d_in[9];
    const float* kn_b  = (const float*)d_in[10];
    const float* ib    = (const float*)d_in[11];
    const float* Wo    = (const float*)d_in[12];
    const float* bo    = (const float*)d_in[13];
    const float* gamma = (const float*)d_in[14];
    float* out = (float*)d_out;

    char* ws = (char*)d_ws;
    size_t off = 0;
    auto alloc = [&](size_t bytes) -> void* {
        void* p = ws + off;
        off += (bytes + 255) & ~(size_t)255;
        return p;
    };
    u16* xb       = (u16*)alloc((size_t)4096 * 1024 * 2);   // x bf16
    u16* wqkv_t   = (u16*)alloc((size_t)3072 * 1024 * 2);   // [n][k]
    u16* wo_t     = (u16*)alloc((size_t)1024 * 1024 * 2);
    float* bqkv   = (float*)alloc((size_t)3072 * 4);
    u16* qkv_raw  = (u16*)alloc((size_t)4096 * 3072 * 2);   // q|k|v rows
    u16* Qn       = (u16*)alloc((size_t)32 * 2048 * 64 * 2);
    u16* Kn       = (u16*)alloc((size_t)32 * 2048 * 64 * 2);
    u16* Vtp      = (u16*)alloc((size_t)32 * 64 * 2048 * 2);
    u16* attn_out = (u16*)alloc((size_t)4096 * 1024 * 2);

    k_pack_x<<<4096, 256, 0, stream>>>(x, xb, 1048576);
    k_transpose_w<<<dim3(32, 32, 4), 256, 0, stream>>>(Wq, Wk, Wv, Wo, wqkv_t, wo_t);
    k_pack_bias<<<12, 256, 0, stream>>>(bq, bk, bv, bqkv);
    k_gemm<0><<<dim3(32, 24), 256, 0, stream>>>(xb, wqkv_t, bqkv, nullptr, qkv_raw, 3072);
    k_ln_repack<<<dim3(32, 32), 256, 0, stream>>>(qkv_raw, qn_s, qn_b, kn_s, kn_b, Qn, Kn, Vtp);
    k_attn<<<dim3(32, 32), 256, 0, stream>>>(Qn, Kn, Vtp, ib, attn_out);
    k_gemm<1><<<dim3(32, 8), 256, 0, stream>>>(attn_out, wo_t, bo, gamma, out, 1024);
}